// Round 8
// baseline (329.769 us; speedup 1.0000x reference)
//
#include <hip/hip_runtime.h>
#include <cfloat>
#include <math.h>

namespace {
constexpr int Bn = 4, Cin = 8, Pn = 12000, Nn = 64, Co = 64, Hh = 282, Ww = 282;
constexpr int NPIL  = Bn * Pn;
constexpr int NCELL = Hh * Ww;
constexpr int CHW   = Pn * Nn;
constexpr double CNTD = (double)Bn * Pn * Nn;
constexpr int K1B = 1024;               // k1_momfeat blocks per input
constexpr int WL_CAP = 48000;           // max occupied cells per input
constexpr int APPLY_B = (WL_CAP + 255) / 256;
constexpr int FILL_B = (Bn * Co * NCELL / 4) / 256;   // 19881, exact

// Workspace layout. part (k1 partials, 360448 B) aliases the wl region:
// part is dead after k1b_reduce, and k_compact (which writes wlS/wlM) runs
// strictly after k1b/k2/negfix in stream order.
constexpr size_t PAR_OFF  = 0;                          // 2*128 floats = 1024
constexpr size_t MOM_OFF  = 1024;                       // 88 doubles
constexpr size_t HDR_OFF  = 2048;                       // 8 ints
constexpr size_t WLS_OFF  = 8192;                       // WL_CAP int2 = 384000
constexpr size_t PART_OFF = WLS_OFF;                    // alias (see above)
constexpr size_t WLM_OFF  = WLS_OFF + (size_t)WL_CAP * 8;    // 392192
constexpr size_t WIN_OFF  = WLM_OFF + (size_t)WL_CAP * 8;    // 776192
constexpr size_t YMAX_OFF = WIN_OFF + (size_t)2 * Bn * NCELL * 4; // 3320960
constexpr size_t WS_NEED  = YMAX_OFF + (size_t)2 * NPIL * 64 * 4; // 27896960

typedef __attribute__((ext_vector_type(8))) float f32x8_t;

// Grid mapping matched to XLA's canonicalization: division by 0.16 becomes
// multiplication by the EXACT reciprocal 6.25 (rcp(0.16f) rounds to 6.25f).
// f32-div differs by ~0.3ulp -> O(1) pillars land one cell off (the 2.62 bug).
__device__ __forceinline__ int cell_of(float xc, float yc) {
  int xg = (int)floorf((xc + 22.0f) * 6.25f);
  int yg = (int)floorf((yc + 22.0f) * 6.25f);
  xg = min(max(xg, 0), Ww - 1);
  yg = min(max(yg, 0), Hh - 1);
  return yg * Ww + xg;
}

__device__ __forceinline__ float firstlane(float v) {
  return __int_as_float(__builtin_amdgcn_readfirstlane(__float_as_int(v)));
}

// Cross-lane xor-1 / xor-2 on the VALU via DPP quad_perm (no DS pipe).
__device__ __forceinline__ float dpp_xor1(float v) {
  return __int_as_float(__builtin_amdgcn_update_dpp(
      0, __float_as_int(v), 0xB1, 0xF, 0xF, true));
}
__device__ __forceinline__ float dpp_xor2(float v) {
  return __int_as_float(__builtin_amdgcn_update_dpp(
      0, __float_as_int(v), 0x4E, 0xF, 0xF, true));
}
}

__global__ void kdiag(float* __restrict__ out, float v) {
  if (threadIdx.x == 0 && blockIdx.x == 0) out[0] = v;
}

// Merged bias-fill (blocks [0,FILL_B)) + winners/hdr init (blocks >= FILL_B).
__global__ __launch_bounds__(256) void kinit_fill(
    const float* __restrict__ b_bb, float* __restrict__ out,
    int* __restrict__ winners, int* __restrict__ hdr)
{
  if (blockIdx.x < FILL_B) {
    const int idx = blockIdx.x * 256 + threadIdx.x;
    const int plane = idx / (NCELL / 4);      // b*Co + o
    const float v = b_bb[plane & 63];
    ((float4*)out)[idx] = make_float4(v, v, v, v);
  } else {
    const int t = (blockIdx.x - FILL_B) * 256 + threadIdx.x;
    if (t < 8) hdr[t] = 0;
    for (int i = t; i < 2 * Bn * NCELL; i += 256 * 256) winners[i] = -1;
  }
}

// FUSED: moments + pillar->cell scatter + RAW PFN matmul + max-over-points.
// Blocks [0,K1B) -> sweep, [K1B,2*K1B) -> map. One pillar per wave-iteration,
// lane = point index n; xv[c] (loaded once) feeds BOTH the moment accumulators
// and the matmul. Matmul uses the RAW weights w,b (known before moments!):
// y[o,n] = b[o] + sum_c w[o][c] x[c][n] -- the exact R0 fmaf chain. Only
// ymax[o] = max_n y[o,n] is stored (fmax is order-exact); LN+ReLU is applied
// later via the monotone identity max_n fma(a,y_n,cc) = fma(a, max_n y, cc)
// (a<0 handled by k_negfix). Weights delivered per 8-channel chunk via one
// inline-asm block of s_loads -> SGPRs (scalar-cache hits, same pattern as
// the proven R5 kernel); inner loop is v_fma with one scalar operand.
__global__ __launch_bounds__(256) void k1_momfeat(
    const float* __restrict__ sweep, const float* __restrict__ map_in,
    const float* __restrict__ w_s, const float* __restrict__ b_s,
    const float* __restrict__ w_m, const float* __restrict__ b_m,
    float* __restrict__ partOut, int* __restrict__ winners,
    float* __restrict__ ymax)
{
  __shared__ float red[4][44];
  const int lane = threadIdx.x & 63;
  const int wv   = threadIdx.x >> 6;
  const int bid2 = blockIdx.x & (K1B - 1);
  const int inp  = blockIdx.x / K1B;
  const float* x  = inp ? map_in : sweep;
  const float* w  = inp ? w_m : w_s;
  const float* bb = inp ? b_m : b_s;
  int*   win = winners + inp * Bn * NCELL;
  float* ym  = ymax + (size_t)inp * NPIL * 64;
  const int gw   = (bid2 * 256 + (int)threadIdx.x) >> 6;
  const int nw   = (K1B * 256) >> 6;

  float sacc[8];
  float macc[36];
#pragma unroll
  for (int i = 0; i < 8; ++i) sacc[i] = 0.f;
#pragma unroll
  for (int i = 0; i < 36; ++i) macc[i] = 0.f;

  const int l0 = lane & 1, l1 = (lane >> 1) & 1, l2 = (lane >> 2) & 1;

  for (int pp = gw; pp < NPIL; pp += nw) {
    const int b = pp / Pn;
    const int p = pp - b * Pn;
    const float* xb = x + (size_t)b * Cin * CHW + (size_t)p * Nn + lane;
    float xv[Cin];
#pragma unroll
    for (int c = 0; c < Cin; ++c) xv[c] = xb[(size_t)c * CHW];

    // ---- moments (unchanged chains -> bit-identical moments) ----
#pragma unroll
    for (int c = 0; c < Cin; ++c) sacc[c] += xv[c];
    {
      int k = 0;
#pragma unroll
      for (int i = 0; i < 8; ++i)
#pragma unroll
        for (int j = i; j < 8; ++j) { macc[k] = fmaf(xv[i], xv[j], macc[k]); ++k; }
    }

    // ---- fused scatter ----
    const float xc = firstlane(xv[0]);
    if (xc != 0.0f) {
      const float yc = firstlane(xv[1]);
      if (lane == 0) atomicMax(&win[b * NCELL + cell_of(xc, yc)], p);
    }

    // ---- raw matmul + max-over-points ----
    float res = 0.f;
#pragma unroll
    for (int g = 0; g < 8; ++g) {
      f32x8_t wr0, wr1, wr2, wr3, wr4, wr5, wr6, wr7, b8;
      asm("s_load_dwordx8 %0, %9, 0x0\n\t"
          "s_load_dwordx8 %1, %9, 0x20\n\t"
          "s_load_dwordx8 %2, %9, 0x40\n\t"
          "s_load_dwordx8 %3, %9, 0x60\n\t"
          "s_load_dwordx8 %4, %9, 0x80\n\t"
          "s_load_dwordx8 %5, %9, 0xA0\n\t"
          "s_load_dwordx8 %6, %9, 0xC0\n\t"
          "s_load_dwordx8 %7, %9, 0xE0\n\t"
          "s_load_dwordx8 %8, %10, 0x0\n\t"
          "s_waitcnt lgkmcnt(0)"
          : "=&s"(wr0), "=&s"(wr1), "=&s"(wr2), "=&s"(wr3), "=&s"(wr4),
            "=&s"(wr5), "=&s"(wr6), "=&s"(wr7), "=&s"(b8)
          : "s"(w + g * 64), "s"(bb + g * 8));

      float z[8];
#define PFN_ROW(J, WR)                                                        \
      {                                                                       \
        float y = b8[J];                                                      \
        _Pragma("unroll")                                                     \
        for (int c = 0; c < Cin; ++c) y = fmaf(WR[c], xv[c], y);              \
        z[J] = y;                                                             \
      }
      PFN_ROW(0, wr0) PFN_ROW(1, wr1) PFN_ROW(2, wr2) PFN_ROW(3, wr3)
      PFN_ROW(4, wr4) PFN_ROW(5, wr5) PFN_ROW(6, wr6) PFN_ROW(7, wr7)
#undef PFN_ROW

      // reduce-scatter max (proven R7 tree; fmax is order-exact)
      float t0[4];
#pragma unroll
      for (int i = 0; i < 4; ++i) {
        const float send = l0 ? z[2 * i] : z[2 * i + 1];
        const float keep = l0 ? z[2 * i + 1] : z[2 * i];
        t0[i] = fmaxf(keep, dpp_xor1(send));
      }
      float t1[2];
#pragma unroll
      for (int i = 0; i < 2; ++i) {
        const float send = l1 ? t0[2 * i] : t0[2 * i + 1];
        const float keep = l1 ? t0[2 * i + 1] : t0[2 * i];
        t1[i] = fmaxf(keep, dpp_xor2(send));
      }
      {
        const float send = l2 ? t1[0] : t1[1];
        const float keep = l2 ? t1[1] : t1[0];
        float v = fmaxf(keep, __shfl_xor(send, 4, 64));
        v = fmaxf(v, __shfl_xor(v, 8, 64));
        v = fmaxf(v, __shfl_xor(v, 16, 64));
        v = fmaxf(v, __shfl_xor(v, 32, 64));
        if ((lane >> 3) == g) res = v;
      }
    }
    ym[(size_t)pp * 64 + lane] = res;   // RAW ymax (no relu; affine later)
  }

  // ---- moment partial reduction (unchanged) ----
#pragma unroll
  for (int k = 0; k < 44; ++k) {
    float v = (k < 8) ? sacc[k] : macc[k - 8];
#pragma unroll
    for (int off = 32; off > 0; off >>= 1) v += __shfl_down(v, off, 64);
    if (lane == 0) red[wv][k] = v;
  }
  __syncthreads();
  if (threadIdx.x < 44) {
    const float s = red[0][threadIdx.x] + red[1][threadIdx.x] +
                    red[2][threadIdx.x] + red[3][threadIdx.x];
    partOut[(size_t)bid2 * 88 + inp * 44 + threadIdx.x] = s;
  }
}

// One block per moment component; 256-thread tree reduction in double.
__global__ __launch_bounds__(256) void k1b_reduce(
    const float* __restrict__ part, double* __restrict__ mom)
{
  __shared__ double sd[256];
  const int t = blockIdx.x;              // 0..87
  double s = 0.0;
  for (int blk = threadIdx.x; blk < K1B; blk += 256)
    s += (double)part[(size_t)blk * 88 + t];
  sd[threadIdx.x] = s;
  __syncthreads();
  for (int off = 128; off > 0; off >>= 1) {
    if (threadIdx.x < off) sd[threadIdx.x] += sd[threadIdx.x + off];
    __syncthreads();
  }
  if (threadIdx.x == 0) mom[t] = sd[0];
}

// LN params (double precision), R0 form: a = gamma/sqrt(var+eps),
// cc = beta - mean*a. par layout per input: a[64] then cc[64].
// Publishes a per-channel sign mask (hdr[4..7]) for the a<0 path.
__global__ void k2_params(const double* __restrict__ mom,
    const float* __restrict__ w_s, const float* __restrict__ b_s,
    const float* __restrict__ g_s, const float* __restrict__ be_s,
    const float* __restrict__ w_m, const float* __restrict__ b_m,
    const float* __restrict__ g_m, const float* __restrict__ be_m,
    float* __restrict__ par, int* __restrict__ hdr)
{
  const int t = threadIdx.x;
  if (t >= 128) return;
  const int inp = t >> 6, o = t & 63;
  const double* m = mom + inp * 44;
  const float* w    = (inp ? w_m : w_s) + o * Cin;
  const float bias  = (inp ? b_m : b_s)[o];
  const float gamma = (inp ? g_m : g_s)[o];
  const float beta  = (inp ? be_m : be_s)[o];
  double S[8];
#pragma unroll
  for (int c = 0; c < 8; ++c) S[c] = m[c] / CNTD;
  double mean = (double)bias;
#pragma unroll
  for (int c = 0; c < 8; ++c) mean += (double)w[c] * S[c];
  double var = 0.0;
  int k = 8;
#pragma unroll
  for (int i = 0; i < 8; ++i)
#pragma unroll
    for (int j = i; j < 8; ++j) {
      const double cov = m[k] / CNTD - S[i] * S[j];
      const double ww = (double)w[i] * (double)w[j];
      var += (i == j ? ww : 2.0 * ww) * cov;
      ++k;
    }
  const double a = (double)gamma / sqrt(var + 1e-5);
  const double c = (double)beta - mean * a;
  const float af = (float)a;
  par[inp * 128 + o]      = af;
  par[inp * 128 + 64 + o] = (float)c;
  if (af < 0.f) atomicOr(&hdr[4 + inp * 2 + (o >> 5)], 1 << (o & 31));
}

// a<0 fix-up (gamma<0 is a ~10-sigma event; kernel exits immediately when the
// mask is zero, keeping correctness data-independent): for flagged channels,
// max_n fma(a,y,cc) = fma(a, MIN_n y, cc) -> rewrite ymax[o] := min_n y[o,n].
__global__ __launch_bounds__(256) void k_negfix(
    const float* __restrict__ sweep, const float* __restrict__ map_in,
    const float* __restrict__ w_s, const float* __restrict__ b_s,
    const float* __restrict__ w_m, const float* __restrict__ b_m,
    const int* __restrict__ hdr, float* __restrict__ ymax)
{
  const int inp = blockIdx.x & 1;
  const unsigned m0 = (unsigned)hdr[4 + inp * 2];
  const unsigned m1 = (unsigned)hdr[5 + inp * 2];
  if ((m0 | m1) == 0u) return;
  const float* x  = inp ? map_in : sweep;
  const float* w  = inp ? w_m : w_s;
  const float* bb = inp ? b_m : b_s;
  float* ym = ymax + (size_t)inp * NPIL * 64;
  const int lane = threadIdx.x & 63;
  const int wv   = threadIdx.x >> 6;
  const int gw   = (int)(blockIdx.x >> 1) * 4 + wv;
  const int nw   = (int)(gridDim.x >> 1) * 4;
  for (int pp = gw; pp < NPIL; pp += nw) {
    const int b = pp / Pn;
    const int p = pp - b * Pn;
    const size_t base = (size_t)b * Cin * CHW + (size_t)p * Nn;
    float xv[Cin];
#pragma unroll
    for (int c = 0; c < Cin; ++c) xv[c] = x[base + (size_t)c * CHW + lane];
    for (int half = 0; half < 2; ++half) {
      unsigned m = half ? m1 : m0;
      while (m) {
        const int bit = __ffs(m) - 1;
        m &= m - 1;
        const int o = half * 32 + bit;
        float y = bb[o];
#pragma unroll
        for (int c = 0; c < Cin; ++c) y = fmaf(w[o * Cin + c], xv[c], y);
#pragma unroll
        for (int s = 1; s < 64; s <<= 1) y = fminf(y, __shfl_xor(y, s, 64));
        if (lane == 0) ym[(size_t)pp * 64 + o] = y;
      }
    }
  }
}

// Build packed worklists (per input), BLOCK-ORDERED: ballot scan + one
// atomicAdd per block per list. Entry = {outbase, featrow = b*Pn + p}.
// hdr[1]/hdr[2] double as the occupancy diagnostic.
__global__ __launch_bounds__(256) void k_compact(
    const int* __restrict__ winners, int* __restrict__ hdr,
    int2* __restrict__ wlS, int2* __restrict__ wlM)
{
  __shared__ int cS[4], cM[4];
  __shared__ int baseS, baseM;
  const int t = blockIdx.x * 256 + threadIdx.x;
  const int lane = threadIdx.x & 63;
  const int wv   = threadIdx.x >> 6;
  int ps = -1, pm = -1, outbase = 0, b = 0;
  if (t < Bn * NCELL) {
    b = t / NCELL;
    const int hw = t - b * NCELL;
    outbase = b * Co * NCELL + hw;
    ps = winners[t];
    pm = winners[Bn * NCELL + t];
  }
  const unsigned long long ms = __ballot(ps >= 0);
  const unsigned long long mm = __ballot(pm >= 0);
  if (lane == 0) { cS[wv] = __popcll(ms); cM[wv] = __popcll(mm); }
  __syncthreads();
  if (threadIdx.x == 0) {
    const int c = cS[0] + cS[1] + cS[2] + cS[3];
    baseS = c ? atomicAdd(&hdr[1], c) : 0;
  } else if (threadIdx.x == 64) {
    const int c = cM[0] + cM[1] + cM[2] + cM[3];
    baseM = c ? atomicAdd(&hdr[2], c) : 0;
  }
  __syncthreads();
  const unsigned long long below = (1ull << lane) - 1ull;
  if (ps >= 0) {
    int off = baseS + __popcll(ms & below);
    for (int w2 = 0; w2 < wv; ++w2) off += cS[w2];
    wlS[off] = make_int2(outbase, b * Pn + ps);
  }
  if (pm >= 0) {
    int off = baseM + __popcll(mm & below);
    for (int w2 = 0; w2 < wv; ++w2) off += cM[w2];
    wlM[off] = make_int2(outbase, b * Pn + pm);
  }
}

// Dense matvec over the compacted worklist, with the LN affine+ReLU applied
// INLINE from ymax: f[o] = relu(fma(a[o], ymax[o], cc[o])) -- identical values
// to the previously-stored feats, then the identical fmaf dot-product chain.
// WHICH=0 (sweep): out = bias + W[:,0:64]·f   (overwrite after fill)
// WHICH=1 (map):   out +=        W[:,64:128]·f (RMW, runs after WHICH=0)
template<int WHICH>
__global__ __launch_bounds__(256) void k_apply(
    const int* __restrict__ hdr, const int2* __restrict__ wl,
    const float* __restrict__ ymax, const float* __restrict__ par,
    const float* __restrict__ w_bb, const float* __restrict__ b_bb,
    float* __restrict__ out)
{
  __shared__ float4 wlds[Co * 16];
  __shared__ float bbb[Co];
  __shared__ float av[Co], cv[Co];
  for (int i = threadIdx.x; i < Co * 16; i += 256)
    wlds[i] = ((const float4*)w_bb)[((i >> 4) << 5) + (WHICH ? 16 : 0) + (i & 15)];
  if (threadIdx.x < Co) {
    bbb[threadIdx.x] = b_bb[threadIdx.x];
    av[threadIdx.x]  = par[WHICH * 128 + threadIdx.x];
    cv[threadIdx.x]  = par[WHICH * 128 + 64 + threadIdx.x];
  }
  __syncthreads();
  const float* ybase = ymax + (size_t)WHICH * NPIL * 64;
  const int cnt = hdr[1 + WHICH];
  for (int i = blockIdx.x * blockDim.x + threadIdx.x; i < cnt;
       i += gridDim.x * blockDim.x) {
    const int2 e = wl[i];
    const float4* yp = (const float4*)(ybase + (size_t)e.y * 64);
    float4 f[16];
#pragma unroll
    for (int k = 0; k < 16; ++k) {
      const float4 ymv = yp[k];
      f[k].x = fmaxf(fmaf(av[4 * k + 0], ymv.x, cv[4 * k + 0]), 0.f);
      f[k].y = fmaxf(fmaf(av[4 * k + 1], ymv.y, cv[4 * k + 1]), 0.f);
      f[k].z = fmaxf(fmaf(av[4 * k + 2], ymv.z, cv[4 * k + 2]), 0.f);
      f[k].w = fmaxf(fmaf(av[4 * k + 3], ymv.w, cv[4 * k + 3]), 0.f);
    }
    float* op = out + e.x;
#pragma unroll 2
    for (int o = 0; o < Co; ++o) {
      float acc = WHICH ? op[(size_t)o * NCELL] : bbb[o];
      const float4* row = &wlds[o * 16];
#pragma unroll
      for (int k = 0; k < 16; ++k) {
        const float4 w4 = row[k];
        acc = fmaf(w4.x, f[k].x, acc); acc = fmaf(w4.y, f[k].y, acc);
        acc = fmaf(w4.z, f[k].z, acc); acc = fmaf(w4.w, f[k].w, acc);
      }
      op[(size_t)o * NCELL] = acc;
    }
  }
}

__global__ void k6_verdict(const int* __restrict__ hdr, float* __restrict__ out)
{
  if (threadIdx.x != 0 || blockIdx.x != 0) return;
  const int n_occ = hdr[1] + hdr[2];
  if (n_occ < 80000 || n_occ > 96000) out[0] = 1.0e7f + (float)n_occ;
}

extern "C" void kernel_launch(void* const* d_in, const int* in_sizes, int n_in,
                              void* d_out, int out_size, void* d_ws, size_t ws_size,
                              hipStream_t stream)
{
  const float* sweep  = (const float*)d_in[0];
  const float* map_in = (const float*)d_in[1];
  const float* w_s  = (const float*)d_in[2];
  const float* b_s  = (const float*)d_in[3];
  const float* g_s  = (const float*)d_in[4];
  const float* be_s = (const float*)d_in[5];
  const float* w_m  = (const float*)d_in[6];
  const float* b_m  = (const float*)d_in[7];
  const float* g_m  = (const float*)d_in[8];
  const float* be_m = (const float*)d_in[9];
  const float* w_bb = (const float*)d_in[10];
  const float* b_bb = (const float*)d_in[11];
  float* out = (float*)d_out;

  const int exp_sz[12] = {24576000, 24576000, 512, 64, 64, 64, 512, 64, 64, 64, 8192, 64};
  int bad_idx = -1;
  if (n_in != 12) bad_idx = 11;
  else for (int i = 0; i < 12; ++i) if (in_sizes[i] != exp_sz[i]) { bad_idx = i; break; }
  if (bad_idx >= 0) {
    kdiag<<<1, 1, 0, stream>>>(out, 9.0e7f + 1.0e5f * (float)bad_idx);
    return;
  }
  if (ws_size < WS_NEED) {
    kdiag<<<1, 1, 0, stream>>>(out, 8.0e7f);
    return;
  }

  char* ws = (char*)d_ws;
  float*  par     = (float*)(ws + PAR_OFF);
  double* mom     = (double*)(ws + MOM_OFF);
  int*    hdr     = (int*)(ws + HDR_OFF);
  int*    winners = (int*)(ws + WIN_OFF);
  float*  ymax    = (float*)(ws + YMAX_OFF);
  float*  part    = (float*)(ws + PART_OFF);
  int2*   wlS     = (int2*)(ws + WLS_OFF);
  int2*   wlM     = (int2*)(ws + WLM_OFF);

  kinit_fill<<<FILL_B + 256, 256, 0, stream>>>(b_bb, out, winners, hdr);
  k1_momfeat<<<2 * K1B, 256, 0, stream>>>(sweep, map_in, w_s, b_s, w_m, b_m,
                                          part, winners, ymax);
  k1b_reduce<<<88, 256, 0, stream>>>(part, mom);
  k2_params<<<1, 128, 0, stream>>>(mom, w_s, b_s, g_s, be_s, w_m, b_m, g_m, be_m,
                                   par, hdr);
  k_negfix<<<1024, 256, 0, stream>>>(sweep, map_in, w_s, b_s, w_m, b_m, hdr, ymax);
  k_compact<<<(Bn * NCELL + 255) / 256, 256, 0, stream>>>(winners, hdr, wlS, wlM);
  k_apply<0><<<APPLY_B, 256, 0, stream>>>(hdr, wlS, ymax, par, w_bb, b_bb, out);
  k_apply<1><<<APPLY_B, 256, 0, stream>>>(hdr, wlM, ymax, par, w_bb, b_bb, out);
  k6_verdict<<<1, 1, 0, stream>>>(hdr, out);
}